// Round 1
// baseline (359.530 us; speedup 1.0000x reference)
//
#include <hip/hip_runtime.h>
#include <stdint.h>

typedef unsigned short u16;
typedef __attribute__((ext_vector_type(8))) short short8;
typedef __attribute__((ext_vector_type(4))) float f32x4;

#define M_DIM 8192
#define N_DIM 4096
#define K_DIM 4096

#define BM 128
#define BN 128
#define BK 32

// ---------- fp32 -> bf16 (round-to-nearest-even), 8 elems/thread ----------
__device__ inline u16 f32_to_bf16_rne(float f) {
    uint32_t b = __builtin_bit_cast(uint32_t, f);
    b += 0x7fffu + ((b >> 16) & 1u);
    return (u16)(b >> 16);
}

__global__ __launch_bounds__(256)
void cvt_f32_to_bf16_k(const float* __restrict__ in, u16* __restrict__ out, int n_vec8) {
    int stride = gridDim.x * blockDim.x;
    for (int i = blockIdx.x * blockDim.x + threadIdx.x; i < n_vec8; i += stride) {
        const float4* p = reinterpret_cast<const float4*>(in) + 2 * (size_t)i;
        float4 a = p[0];
        float4 b = p[1];
        float v[8] = {a.x, a.y, a.z, a.w, b.x, b.y, b.z, b.w};
        short8 r;
#pragma unroll
        for (int j = 0; j < 8; ++j) r[j] = (short)f32_to_bf16_rne(v[j]);
        *reinterpret_cast<short8*>(out + 8 * (size_t)i) = r;
    }
}

// ---------- bf16 MFMA GEMM, m97 structure ----------
// A: [M][K] bf16 (x), B: [N][K] bf16 (weight, already B^T layout), C: [M][N] f32
__global__ __launch_bounds__(256, 2)
void sparse_linear_gemm(const u16* __restrict__ A, const u16* __restrict__ B,
                        const float* __restrict__ bias, float* __restrict__ C) {
    __shared__ __align__(16) u16 As[BM * BK];   // 8 KiB, linear (global_load_lds dest)
    __shared__ __align__(16) u16 Bs[BN * BK];   // 8 KiB

    const int tid  = threadIdx.x;
    const int wave = tid >> 6;
    const int lane = tid & 63;

    const int brow = blockIdx.y * BM;
    const int bcol = blockIdx.x * BN;

    const int wr = wave >> 1;   // wave row (0..1), owns 64 output rows
    const int wc = wave & 1;    // wave col (0..1), owns 64 output cols

    // staging geometry: tile is 128 rows x 64 bytes; u in [0,512) covers 16B chunks
    const int u0 = tid;
    const int u1 = 256 + tid;
    const int row0 = u0 >> 2, col0 = (u0 & 3) * 8;   // col in bf16 elements
    const int row1 = u1 >> 2, col1 = (u1 & 3) * 8;

    const u16* ag0 = A + (size_t)(brow + row0) * K_DIM + col0;
    const u16* ag1 = A + (size_t)(brow + row1) * K_DIM + col1;
    const u16* bg0 = B + (size_t)(bcol + row0) * K_DIM + col0;
    const u16* bg1 = B + (size_t)(bcol + row1) * K_DIM + col1;

    // wave-uniform LDS bases (HW adds lane*16 bytes)
    u16* asl0 = As + (0   + wave * 64) * 8;
    u16* asl1 = As + (256 + wave * 64) * 8;
    u16* bsl0 = Bs + (0   + wave * 64) * 8;
    u16* bsl1 = Bs + (256 + wave * 64) * 8;

    const int ar = wr * 64 + (lane & 15);   // A-fragment base row
    const int br = wc * 64 + (lane & 15);   // B-fragment base row
    const int kc = (lane >> 4) * 8;         // k offset within BK

    f32x4 acc[4][4];
#pragma unroll
    for (int m = 0; m < 4; ++m)
#pragma unroll
        for (int n = 0; n < 4; ++n) acc[m][n] = (f32x4){0.f, 0.f, 0.f, 0.f};

    for (int k0 = 0; k0 < K_DIM; k0 += BK) {
        __builtin_amdgcn_global_load_lds(
            (const __attribute__((address_space(1))) uint32_t*)(ag0 + k0),
            (__attribute__((address_space(3))) uint32_t*)asl0, 16, 0, 0);
        __builtin_amdgcn_global_load_lds(
            (const __attribute__((address_space(1))) uint32_t*)(ag1 + k0),
            (__attribute__((address_space(3))) uint32_t*)asl1, 16, 0, 0);
        __builtin_amdgcn_global_load_lds(
            (const __attribute__((address_space(1))) uint32_t*)(bg0 + k0),
            (__attribute__((address_space(3))) uint32_t*)bsl0, 16, 0, 0);
        __builtin_amdgcn_global_load_lds(
            (const __attribute__((address_space(1))) uint32_t*)(bg1 + k0),
            (__attribute__((address_space(3))) uint32_t*)bsl1, 16, 0, 0);
        __syncthreads();   // compiler drains vmcnt before barrier

        short8 af[4], bf[4];
#pragma unroll
        for (int m = 0; m < 4; ++m)
            af[m] = *reinterpret_cast<const short8*>(&As[(ar + m * 16) * BK + kc]);
#pragma unroll
        for (int n = 0; n < 4; ++n)
            bf[n] = *reinterpret_cast<const short8*>(&Bs[(br + n * 16) * BK + kc]);

#pragma unroll
        for (int m = 0; m < 4; ++m)
#pragma unroll
            for (int n = 0; n < 4; ++n)
                acc[m][n] = __builtin_amdgcn_mfma_f32_16x16x32_bf16(af[m], bf[n], acc[m][n], 0, 0, 0);

        __syncthreads();
    }

    // epilogue: C/D layout col = lane&15, row = (lane>>4)*4 + reg  [m89-verified]
    const int orow = brow + wr * 64 + (lane >> 4) * 4;
    const int ocol = bcol + wc * 64 + (lane & 15);
#pragma unroll
    for (int n = 0; n < 4; ++n) {
        const int c = ocol + n * 16;
        const float bv = bias[c];
#pragma unroll
        for (int m = 0; m < 4; ++m) {
#pragma unroll
            for (int j = 0; j < 4; ++j) {
                const int r = orow + m * 16 + j;
                C[(size_t)r * N_DIM + c] = acc[m][n][j] + bv;
            }
        }
    }
}

// ---------- fallback (only if d_ws too small): correct, slow fp32 ----------
__global__ __launch_bounds__(256)
void gemm_f32_naive(const float* __restrict__ x, const float* __restrict__ w,
                    const float* __restrict__ bias, float* __restrict__ out) {
    const size_t total = (size_t)M_DIM * N_DIM;
    const size_t stride = (size_t)gridDim.x * blockDim.x;
    for (size_t idx = (size_t)blockIdx.x * blockDim.x + threadIdx.x; idx < total; idx += stride) {
        const int b = (int)(idx / N_DIM);
        const int o = (int)(idx % N_DIM);
        const float* xr = x + (size_t)b * K_DIM;
        const float* wr = w + (size_t)o * K_DIM;
        float s = bias[o];
        for (int k = 0; k < K_DIM; ++k) s = fmaf(xr[k], wr[k], s);
        out[idx] = s;
    }
}

extern "C" void kernel_launch(void* const* d_in, const int* in_sizes, int n_in,
                              void* d_out, int out_size, void* d_ws, size_t ws_size,
                              hipStream_t stream) {
    const float* x    = (const float*)d_in[0];
    const float* w    = (const float*)d_in[1];
    const float* bias = (const float*)d_in[2];
    float* out = (float*)d_out;

    const size_t xb_elems = (size_t)M_DIM * K_DIM;
    const size_t wb_elems = (size_t)N_DIM * K_DIM;
    const size_t need = (xb_elems + wb_elems) * sizeof(u16);

    if (ws_size >= need) {
        u16* xb = (u16*)d_ws;
        u16* wb = xb + xb_elems;
        cvt_f32_to_bf16_k<<<2048, 256, 0, stream>>>(x, xb, (int)(xb_elems / 8));
        cvt_f32_to_bf16_k<<<2048, 256, 0, stream>>>(w, wb, (int)(wb_elems / 8));
        dim3 grid(N_DIM / BN, M_DIM / BM);   // (32, 64) = 2048 blocks
        sparse_linear_gemm<<<grid, 256, 0, stream>>>(xb, wb, bias, out);
    } else {
        gemm_f32_naive<<<4096, 256, 0, stream>>>(x, w, bias, out);
    }
}